// Round 1
// baseline (146.728 us; speedup 1.0000x reference)
//
#include <hip/hip_runtime.h>
#include <hip/hip_bf16.h>

typedef unsigned short u16;
typedef __bf16 bf16x8 __attribute__((ext_vector_type(8)));
typedef float f32x4 __attribute__((ext_vector_type(4)));
typedef unsigned short ushort8 __attribute__((ext_vector_type(8)));

#define C_IN   128
#define C_OUT  256
#define BATCH  16
#define LEN    4096
#define KS     9
#define PAD    4
#define LPAD   (LEN + 2*PAD)      // 4104
#define KTOT   (C_IN * KS)        // 1152

__device__ inline u16 f2bf(float f) {
    __hip_bfloat16 h = __float2bfloat16(f);
    return __builtin_bit_cast(u16, h);
}

// ---------------------------------------------------------------------------
// Prep 1: x [B][C][L] f32  ->  x_t [B][LPAD][C] bf16, edge-padded, with the
// XOR swizzle (16B-block index ^= (l&7)) pre-baked into the global layout so
// the main kernel can stage LDS linearly and read swizzled (rule #21).
// ---------------------------------------------------------------------------
__global__ void prep_xt(const float* __restrict__ x, u16* __restrict__ xt) {
    int b    = blockIdx.y;
    int lane = threadIdx.x & 63;
    int jb   = threadIdx.x >> 6;          // 0..3
    int lp   = blockIdx.x * 64 + lane;    // padded index
    if (lp >= LPAD) return;
    int l = lp - PAD;
    l = l < 0 ? 0 : (l > LEN - 1 ? LEN - 1 : l);   // edge clamp
    const float* xb = x + (size_t)b * C_IN * LEN + l;
    u16* row = xt + ((size_t)b * LPAD + lp) * C_IN;
    int key = lp & 7;
    #pragma unroll
    for (int jj = 0; jj < 4; ++jj) {
        int cblk = jb * 4 + jj;            // channel 16B-block 0..15
        ushort8 v;
        #pragma unroll
        for (int e = 0; e < 8; ++e)
            v[e] = f2bf(xb[(size_t)(cblk * 8 + e) * LEN]);   // coalesced over lanes
        int jstore = cblk ^ key;           // pre-swizzled position
        *reinterpret_cast<ushort8*>(row + jstore * 8) = v;
    }
}

// ---------------------------------------------------------------------------
// Prep 2: weight [O][C][KS] f32 -> w2 [O][k*128+c] bf16 (A-frags contiguous)
// ---------------------------------------------------------------------------
__global__ void prep_w2(const float* __restrict__ w, u16* __restrict__ w2) {
    int i = blockIdx.x * 256 + threadIdx.x;
    if (i >= C_OUT * KTOT) return;
    int o = i / KTOT, r = i % KTOT;
    int k = r >> 7, c = r & 127;
    w2[i] = f2bf(w[(size_t)o * KTOT + c * KS + k]);
}

// ---------------------------------------------------------------------------
// Prep 3: ebias[o] = bias[o] + sum_{c,k} offset[c,k]*W[o,c,k];  phys scalar.
// ---------------------------------------------------------------------------
__global__ void prep_ebias(const float* __restrict__ w, const float* __restrict__ bias,
                           const float* __restrict__ vel, const float* __restrict__ acc,
                           float* __restrict__ ebias, float* __restrict__ phys_out) {
    __shared__ float off_s[KTOT];
    __shared__ float red[256];
    int t = threadIdx.x;
    float pv = 0.f;
    for (int i = t; i < KTOT; i += 256) {
        int k = i % KS;                    // layout [c][k]
        float tk = k * 0.01f;              // DT
        float v = vel[i], a = acc[i];
        off_s[i] = v * tk + 0.5f * a * tk * tk;
        pv += v * v + a * a;
    }
    red[t] = pv;
    __syncthreads();
    for (int s2 = 128; s2 > 0; s2 >>= 1) {
        if (t < s2) red[t] += red[t + s2];
        __syncthreads();
    }
    if (t == 0) *phys_out = 0.01f * (red[0] / (float)KTOT);  // REG*(mean+mean)
    float sum = bias[t];
    for (int i = 0; i < KTOT; ++i)
        sum += off_s[i] * w[(size_t)t * KTOT + i];
    ebias[t] = sum;
}

// ---------------------------------------------------------------------------
// Main: implicit-GEMM conv. Block = 128 o x 128 l, 4 waves (2x2), each wave
// 4x4 frags of mfma_f32_16x16x32_bf16. x-tile staged once in LDS (136x128
// bf16, swizzle baked in layout); A-frags streamed from L2-resident w2.
// ---------------------------------------------------------------------------
__global__ __launch_bounds__(256) void conv_main(const u16* __restrict__ xt,
                                                 const u16* __restrict__ w2,
                                                 const float* __restrict__ ebias,
                                                 float* __restrict__ out) {
    __shared__ u16 ldsx[136 * 128];        // 34816 B

    int b     = blockIdx.z;
    int obase = blockIdx.y * 128;
    int lbase = blockIdx.x * 128;
    int t     = threadIdx.x;
    int lane  = t & 63;
    int w     = t >> 6;
    int wm    = w >> 1;                    // wave row (o)
    int wn    = w & 1;                     // wave col (l)

    // ---- stage x tile: linear copy of 136 rows * 256B (swizzle is in data)
    const uint4* src = reinterpret_cast<const uint4*>(xt + ((size_t)b * LPAD + lbase) * C_IN);
    uint4* dst = reinterpret_cast<uint4*>(ldsx);
    for (int u = t; u < 2176; u += 256) dst[u] = src[u];
    __syncthreads();

    f32x4 acc[4][4] = {};
    int mrow = lane & 15;                  // A row / B col within 16
    int kgrp = lane >> 4;                  // 0..3 -> k-subgroup of 8

    const u16* wbase = w2 + (size_t)(obase + wm * 64 + mrow) * KTOT + kgrp * 8;
    const char* ldsbase = reinterpret_cast<const char*>(ldsx);

    for (int s = 0; s < 36; ++s) {         // K = 1152 in steps of 32
        int k  = s >> 2;                   // conv tap 0..8
        int cb = (s & 3) << 5;             // channel base within tap
        bf16x8 afrag[4];
        #pragma unroll
        for (int mi = 0; mi < 4; ++mi)
            afrag[mi] = *reinterpret_cast<const bf16x8*>(wbase + mi * 16 * KTOT + s * 32);
        #pragma unroll
        for (int ni = 0; ni < 4; ++ni) {
            int row  = wn * 64 + ni * 16 + mrow + k;          // l_local + tap
            int addr = row * 256 + ((cb + kgrp * 8) << 1);
            addr ^= (row & 7) << 4;                            // un-swizzle
            bf16x8 bfrag = *reinterpret_cast<const bf16x8*>(ldsbase + addr);
            #pragma unroll
            for (int mi = 0; mi < 4; ++mi)
                acc[mi][ni] = __builtin_amdgcn_mfma_f32_16x16x32_bf16(
                    afrag[mi], bfrag, acc[mi][ni], 0, 0, 0);
        }
    }

    // ---- epilogue: D layout col = lane&15 (l), row = (lane>>4)*4 + r (o)
    #pragma unroll
    for (int mi = 0; mi < 4; ++mi) {
        int o0 = obase + wm * 64 + mi * 16 + kgrp * 4;
        f32x4 eb = *reinterpret_cast<const f32x4*>(ebias + o0);
        #pragma unroll
        for (int ni = 0; ni < 4; ++ni) {
            int l = lbase + wn * 64 + ni * 16 + mrow;
            float* op = out + (size_t)(b * C_OUT + o0) * LEN + l;
            #pragma unroll
            for (int r = 0; r < 4; ++r)
                op[(size_t)r * LEN] = acc[mi][ni][r] + eb[r];
        }
    }
}

extern "C" void kernel_launch(void* const* d_in, const int* in_sizes, int n_in,
                              void* d_out, int out_size, void* d_ws, size_t ws_size,
                              hipStream_t stream) {
    const float* x      = (const float*)d_in[0];
    const float* weight = (const float*)d_in[1];
    const float* bias   = (const float*)d_in[2];
    const float* vel    = (const float*)d_in[3];
    const float* acc    = (const float*)d_in[4];
    float* out = (float*)d_out;

    char* ws = (char*)d_ws;
    u16*  xt    = (u16*)ws;                                   // 16,797,696 B
    u16*  w2    = (u16*)(ws + (size_t)BATCH * LPAD * C_IN * 2);   // 589,824 B
    float* ebias = (float*)(ws + (size_t)BATCH * LPAD * C_IN * 2 + (size_t)C_OUT * KTOT * 2);

    hipLaunchKernelGGL(prep_xt, dim3((LPAD + 63) / 64, BATCH), dim3(256), 0, stream, x, xt);
    hipLaunchKernelGGL(prep_w2, dim3((C_OUT * KTOT + 255) / 256), dim3(256), 0, stream, weight, w2);
    hipLaunchKernelGGL(prep_ebias, dim3(1), dim3(256), 0, stream,
                       weight, bias, vel, acc, ebias, out + (size_t)BATCH * C_OUT * LEN);
    hipLaunchKernelGGL(conv_main, dim3(LEN / 128, C_OUT / 128, BATCH), dim3(256), 0, stream,
                       xt, w2, ebias, out);
}

// Round 2
// 76.884 us; speedup vs baseline: 1.9084x; 1.9084x over previous
//
#include <hip/hip_runtime.h>
#include <hip/hip_bf16.h>

typedef unsigned short u16;
typedef __bf16 bf16x8 __attribute__((ext_vector_type(8)));
typedef float f32x4 __attribute__((ext_vector_type(4)));
typedef unsigned short ushort8 __attribute__((ext_vector_type(8)));

#define C_IN   128
#define C_OUT  256
#define BATCH  16
#define LEN    4096
#define KS     9
#define PAD    4
#define LPAD   (LEN + 2*PAD)      // 4104
#define KTOT   (C_IN * KS)        // 1152
#define NSTEP  36                 // K = 1152 / 32

__device__ inline u16 f2bf(float f) {
    __hip_bfloat16 h = __float2bfloat16(f);
    return __builtin_bit_cast(u16, h);
}

// ---------------------------------------------------------------------------
// Prep 1: x [B][C][L] f32  ->  x_t [B][LPAD][C] bf16, edge-padded, with the
// XOR swizzle (16B-block index ^= (l&7), low 3 bits) pre-baked in the global
// layout so the main kernel stages LDS linearly and reads swizzled (rule #21).
// ---------------------------------------------------------------------------
__global__ void prep_xt(const float* __restrict__ x, u16* __restrict__ xt) {
    int b    = blockIdx.y;
    int lane = threadIdx.x & 63;
    int jb   = threadIdx.x >> 6;          // 0..3
    int lp   = blockIdx.x * 64 + lane;    // padded index
    if (lp >= LPAD) return;
    int l = lp - PAD;
    l = l < 0 ? 0 : (l > LEN - 1 ? LEN - 1 : l);   // edge clamp
    const float* xb = x + (size_t)b * C_IN * LEN + l;
    u16* row = xt + ((size_t)b * LPAD + lp) * C_IN;
    int key = lp & 7;
    #pragma unroll
    for (int jj = 0; jj < 4; ++jj) {
        int cblk = jb * 4 + jj;            // channel 16B-block 0..15
        ushort8 v;
        #pragma unroll
        for (int e = 0; e < 8; ++e)
            v[e] = f2bf(xb[(size_t)(cblk * 8 + e) * LEN]);   // coalesced over lanes
        int jstore = cblk ^ key;           // pre-swizzled position (low 3 bits)
        *reinterpret_cast<ushort8*>(row + jstore * 8) = v;
    }
}

// ---------------------------------------------------------------------------
// Prep 2: weight [O][C][KS] f32 -> w3 in A-fragment order so each wave A-load
// is one contiguous 1KB region:
//   elem index = ((s*16 + ob16)*64 + mrow*4 + kgrp)*8 + e
//   where o = ob16*16+mrow, k = s>>2, c = (s&3)*32 + kgrp*8 + e.
// ---------------------------------------------------------------------------
__global__ void prep_w3(const float* __restrict__ w, u16* __restrict__ w3) {
    int i = blockIdx.x * 256 + threadIdx.x;
    if (i >= C_OUT * KTOT) return;
    int e  = i & 7;
    int r  = i >> 3;
    int kg = r & 3;
    int mr = (r >> 2) & 15;
    int ob = (r >> 6) & 15;
    int s  = r >> 10;
    int o  = ob * 16 + mr;
    int k  = s >> 2;
    int c  = (s & 3) * 32 + kg * 8 + e;
    w3[i] = f2bf(w[((size_t)o * C_IN + c) * KS + k]);
}

// ---------------------------------------------------------------------------
// Prep 3 (parallel): ebias[o] = bias[o] + sum_{c,k} offset[c,k]*W[o,c,k].
// One block per o, 256-thread tree reduce. Block 0 also computes phys.
// ---------------------------------------------------------------------------
__global__ void prep_ebias(const float* __restrict__ w, const float* __restrict__ bias,
                           const float* __restrict__ vel, const float* __restrict__ acc,
                           float* __restrict__ ebias, float* __restrict__ phys_out) {
    __shared__ float red[256];
    int o = blockIdx.x;
    int t = threadIdx.x;
    float sum = 0.f;
    for (int i = t; i < KTOT; i += 256) {
        int k = i % KS;                    // offset layout [c][k]
        float tk = k * 0.01f;              // DT
        float off = vel[i] * tk + 0.5f * acc[i] * tk * tk;
        sum += off * w[(size_t)o * KTOT + i];
    }
    red[t] = sum;
    __syncthreads();
    for (int h = 128; h > 0; h >>= 1) {
        if (t < h) red[t] += red[t + h];
        __syncthreads();
    }
    if (t == 0) ebias[o] = bias[o] + red[0];

    if (o == 0) {                          // phys on block 0
        __syncthreads();
        float pv = 0.f;
        for (int i = t; i < KTOT; i += 256) {
            float v = vel[i], a = acc[i];
            pv += v * v + a * a;
        }
        red[t] = pv;
        __syncthreads();
        for (int h = 128; h > 0; h >>= 1) {
            if (t < h) red[t] += red[t + h];
            __syncthreads();
        }
        if (t == 0) *phys_out = 0.01f * (red[0] / (float)KTOT);
    }
}

// ---------------------------------------------------------------------------
// Main: implicit-GEMM conv. Block = 128 o x 128 l, 4 waves (2x2), each wave
// 4x4 frags of mfma_f32_16x16x32_bf16. x-tile staged ONCE in LDS (no in-loop
// barriers); A streamed from L2-resident w3 (coalesced 1KB/load); K-loop
// software-pipelined with named double-buffered register prefetch.
// ---------------------------------------------------------------------------
__global__ __launch_bounds__(256, 3) void conv_main(const u16* __restrict__ xt,
                                                    const u16* __restrict__ w3,
                                                    const float* __restrict__ ebias,
                                                    float* __restrict__ out) {
    __shared__ u16 ldsx[136 * 128];        // 34816 B

    int b     = blockIdx.z;
    int obase = blockIdx.y * 128;
    int lbase = blockIdx.x * 128;
    int t     = threadIdx.x;
    int lane  = t & 63;
    int w     = t >> 6;
    int wm    = w >> 1;                    // wave row (o)
    int wn    = w & 1;                     // wave col (l)

    // ---- stage x tile: linear copy of 136 rows * 256B (swizzle is in data)
    const uint4* src = reinterpret_cast<const uint4*>(xt + ((size_t)b * LPAD + lbase) * C_IN);
    uint4* dst = reinterpret_cast<uint4*>(ldsx);
    for (int u = t; u < 2176; u += 256) dst[u] = src[u];
    __syncthreads();

    f32x4 acc[4][4] = {};
    int mrow = lane & 15;
    int kgrp = lane >> 4;
    int ob16 = (obase >> 4) + wm * 4;      // +mi below

    const u16* wlane = w3 + (size_t)mrow * 32 + kgrp * 8;
    const char* ldsbase = reinterpret_cast<const char*>(ldsx);

    #define LOAD_A(S, AF)                                                        \
        {                                                                        \
            const u16* p_ = wlane + (size_t)((S) * 16 + ob16) * 512;             \
            _Pragma("unroll")                                                    \
            for (int mi = 0; mi < 4; ++mi)                                       \
                AF[mi] = *reinterpret_cast<const bf16x8*>(p_ + mi * 512);        \
        }
    #define LOAD_B(S, BF)                                                        \
        {                                                                        \
            int k_ = (S) >> 2;                                                   \
            int coff_ = ((S) & 3) * 64 + kgrp * 16;                              \
            _Pragma("unroll")                                                    \
            for (int ni = 0; ni < 4; ++ni) {                                     \
                int row_  = wn * 64 + ni * 16 + mrow + k_;                       \
                int addr_ = row_ * 256 + coff_;                                  \
                addr_ ^= (row_ & 7) << 4;                                        \
                BF[ni] = *reinterpret_cast<const bf16x8*>(ldsbase + addr_);      \
            }                                                                    \
        }
    #define MFMA16(AF, BF)                                                       \
        {                                                                        \
            _Pragma("unroll")                                                    \
            for (int ni = 0; ni < 4; ++ni)                                       \
                _Pragma("unroll")                                                \
                for (int mi = 0; mi < 4; ++mi)                                   \
                    acc[mi][ni] = __builtin_amdgcn_mfma_f32_16x16x32_bf16(       \
                        AF[mi], BF[ni], acc[mi][ni], 0, 0, 0);                   \
        }

    bf16x8 aA[4], bA[4], aB[4], bB[4];
    LOAD_A(0, aA); LOAD_B(0, bA);

    #pragma unroll 2
    for (int s = 0; s < NSTEP; s += 2) {
        LOAD_A(s + 1, aB); LOAD_B(s + 1, bB);   // prefetch odd step
        MFMA16(aA, bA);
        if (s + 2 < NSTEP) { LOAD_A(s + 2, aA); LOAD_B(s + 2, bA); }  // prefetch next even
        MFMA16(aB, bB);
    }

    // ---- epilogue: D layout col = lane&15 (l), row = (lane>>4)*4 + r (o)
    #pragma unroll
    for (int mi = 0; mi < 4; ++mi) {
        int o0 = obase + wm * 64 + mi * 16 + kgrp * 4;
        f32x4 eb = *reinterpret_cast<const f32x4*>(ebias + o0);
        #pragma unroll
        for (int ni = 0; ni < 4; ++ni) {
            int l = lbase + wn * 64 + ni * 16 + mrow;
            float* op = out + (size_t)(b * C_OUT + o0) * LEN + l;
            #pragma unroll
            for (int r = 0; r < 4; ++r)
                op[(size_t)r * LEN] = acc[mi][ni][r] + eb[r];
        }
    }
    #undef LOAD_A
    #undef LOAD_B
    #undef MFMA16
}

extern "C" void kernel_launch(void* const* d_in, const int* in_sizes, int n_in,
                              void* d_out, int out_size, void* d_ws, size_t ws_size,
                              hipStream_t stream) {
    const float* x      = (const float*)d_in[0];
    const float* weight = (const float*)d_in[1];
    const float* bias   = (const float*)d_in[2];
    const float* vel    = (const float*)d_in[3];
    const float* acc    = (const float*)d_in[4];
    float* out = (float*)d_out;

    char* ws = (char*)d_ws;
    u16*  xt    = (u16*)ws;                                       // 16,797,696 B
    u16*  w3    = (u16*)(ws + (size_t)BATCH * LPAD * C_IN * 2);   // 589,824 B
    float* ebias = (float*)(ws + (size_t)BATCH * LPAD * C_IN * 2 + (size_t)C_OUT * KTOT * 2);

    hipLaunchKernelGGL(prep_xt, dim3((LPAD + 63) / 64, BATCH), dim3(256), 0, stream, x, xt);
    hipLaunchKernelGGL(prep_w3, dim3((C_OUT * KTOT + 255) / 256), dim3(256), 0, stream, weight, w3);
    hipLaunchKernelGGL(prep_ebias, dim3(C_OUT), dim3(256), 0, stream,
                       weight, bias, vel, acc, ebias, out + (size_t)BATCH * C_OUT * LEN);
    hipLaunchKernelGGL(conv_main, dim3(LEN / 128, C_OUT / 128, BATCH), dim3(256), 0, stream,
                       xt, w3, ebias, out);
}

// Round 3
// 63.862 us; speedup vs baseline: 2.2976x; 1.2039x over previous
//
#include <hip/hip_runtime.h>
#include <hip/hip_bf16.h>

typedef unsigned short u16;
typedef __bf16 bf16x8 __attribute__((ext_vector_type(8)));
typedef float f32x4 __attribute__((ext_vector_type(4)));
typedef unsigned short ushort8 __attribute__((ext_vector_type(8)));

#define C_IN   128
#define C_OUT  256
#define BATCH  16
#define LEN    4096
#define KS     9
#define PAD    4
#define LPAD   (LEN + 2*PAD)      // 4104
#define KTOT   (C_IN * KS)        // 1152
#define NSTEP  36                 // K = 1152 / 32

__device__ inline u16 f2bf(float f) {
    __hip_bfloat16 h = __float2bfloat16(f);
    return __builtin_bit_cast(u16, h);
}

// async global->LDS, 16B per lane, wave-uniform LDS base + lane*16
__device__ __forceinline__ void g2l16(const void* g, void* l) {
    __builtin_amdgcn_global_load_lds(
        (const __attribute__((address_space(1))) void*)g,
        (__attribute__((address_space(3))) void*)l, 16, 0, 0);
}

// ---------------------------------------------------------------------------
// Prep 1: x [B][C][L] f32  ->  x_t [B][LPAD][C] bf16, edge-padded, with the
// XOR swizzle (16B-block index ^= (l&7), low 3 bits) pre-baked in the global
// layout so the main kernel stages LDS linearly and reads swizzled (rule #21).
// ---------------------------------------------------------------------------
__global__ void prep_xt(const float* __restrict__ x, u16* __restrict__ xt) {
    int b    = blockIdx.y;
    int lane = threadIdx.x & 63;
    int jb   = threadIdx.x >> 6;          // 0..3
    int lp   = blockIdx.x * 64 + lane;    // padded index
    if (lp >= LPAD) return;
    int l = lp - PAD;
    l = l < 0 ? 0 : (l > LEN - 1 ? LEN - 1 : l);   // edge clamp
    const float* xb = x + (size_t)b * C_IN * LEN + l;
    u16* row = xt + ((size_t)b * LPAD + lp) * C_IN;
    int key = lp & 7;
    #pragma unroll
    for (int jj = 0; jj < 4; ++jj) {
        int cblk = jb * 4 + jj;            // channel 16B-block 0..15
        ushort8 v;
        #pragma unroll
        for (int e = 0; e < 8; ++e)
            v[e] = f2bf(xb[(size_t)(cblk * 8 + e) * LEN]);   // coalesced over lanes
        int jstore = cblk ^ key;           // pre-swizzled position (low 3 bits)
        *reinterpret_cast<ushort8*>(row + jstore * 8) = v;
    }
}

// ---------------------------------------------------------------------------
// Prep 2: weight [O][C][KS] f32 -> w3 in A-fragment order so a step's A-panel
// for 8 consecutive ob16 groups is one contiguous 8KB region:
//   elem index = ((s*16 + ob16)*64 + mrow*4 + kgrp)*8 + e
//   where o = ob16*16+mrow, k = s>>2, c = (s&3)*32 + kgrp*8 + e.
// ---------------------------------------------------------------------------
__global__ void prep_w3(const float* __restrict__ w, u16* __restrict__ w3) {
    int i = blockIdx.x * 256 + threadIdx.x;
    if (i >= C_OUT * KTOT) return;
    int e  = i & 7;
    int r  = i >> 3;
    int kg = r & 3;
    int mr = (r >> 2) & 15;
    int ob = (r >> 6) & 15;
    int s  = r >> 10;
    int o  = ob * 16 + mr;
    int k  = s >> 2;
    int c  = (s & 3) * 32 + kg * 8 + e;
    w3[i] = f2bf(w[((size_t)o * C_IN + c) * KS + k]);
}

// ---------------------------------------------------------------------------
// Prep 3 (parallel): ebias[o] = bias[o] + sum_{c,k} offset[c,k]*W[o,c,k].
// One block per o, 256-thread tree reduce. Block 0 also computes phys.
// ---------------------------------------------------------------------------
__global__ void prep_ebias(const float* __restrict__ w, const float* __restrict__ bias,
                           const float* __restrict__ vel, const float* __restrict__ acc,
                           float* __restrict__ ebias, float* __restrict__ phys_out) {
    __shared__ float red[256];
    int o = blockIdx.x;
    int t = threadIdx.x;
    float sum = 0.f;
    for (int i = t; i < KTOT; i += 256) {
        int k = i % KS;                    // offset layout [c][k]
        float tk = k * 0.01f;              // DT
        float off = vel[i] * tk + 0.5f * acc[i] * tk * tk;
        sum += off * w[(size_t)o * KTOT + i];
    }
    red[t] = sum;
    __syncthreads();
    for (int h = 128; h > 0; h >>= 1) {
        if (t < h) red[t] += red[t + h];
        __syncthreads();
    }
    if (t == 0) ebias[o] = bias[o] + red[0];

    if (o == 0) {                          // phys on block 0
        __syncthreads();
        float pv = 0.f;
        for (int i = t; i < KTOT; i += 256) {
            float v = vel[i], a = acc[i];
            pv += v * v + a * a;
        }
        red[t] = pv;
        __syncthreads();
        for (int h = 128; h > 0; h >>= 1) {
            if (t < h) red[t] += red[t + h];
            __syncthreads();
        }
        if (t == 0) *phys_out = 0.01f * (red[0] / (float)KTOT);
    }
}

// ---------------------------------------------------------------------------
// Main: implicit-GEMM conv. Block = 128 o x 128 l, 4 waves (2x2), each wave
// 4x4 frags of mfma_f32_16x16x32_bf16.
//  - B (x-tile) staged ONCE via global_load_lds (swizzle baked in data)
//  - A (weights) double-buffered in LDS, 8KB/step via global_load_lds,
//    shared by all waves; frags via conflict-free linear ds_read_b128
//  - register double-buffer on top: A/B frags for s+1 read before MFMA(s)
// ---------------------------------------------------------------------------
__global__ __launch_bounds__(256, 3) void conv_main(const u16* __restrict__ xt,
                                                    const u16* __restrict__ w3,
                                                    const float* __restrict__ ebias,
                                                    float* __restrict__ out) {
    __shared__ u16 ldsx[136 * 128];        // B tile, 34816 B
    __shared__ u16 ldsa[2][4096];          // A dbuf, 2 x 8192 B

    int b     = blockIdx.z;
    int obase = blockIdx.y * 128;
    int lbase = blockIdx.x * 128;
    int t     = threadIdx.x;
    int lane  = t & 63;
    int w     = t >> 6;
    int wm    = w >> 1;                    // wave row (o)
    int wn    = w & 1;                     // wave col (l)

    int mrow = lane & 15;
    int kgrp = lane >> 4;

    // A-panel source for this block: 8 ob16 groups starting at obase/16
    const u16* asrc = w3 + (size_t)(obase >> 4) * 512;   // + s*16*512 per step

    // ---- prologue: stage B (34816B) + A(0) via global_load_lds
    {
        const u16* bsrc = xt + ((size_t)b * LPAD + lbase) * C_IN;
        // B: 2176 16B-units, waves interleaved, all-full-wave calls
        #pragma unroll
        for (int j = 0; j < 8; ++j)
            g2l16(bsrc + (j * 256 + t) * 8, ldsx + (j * 256 + w * 64) * 8);
        if (t < 128)
            g2l16(bsrc + (2048 + t) * 8, ldsx + (2048 + w * 64) * 8);
        // A(0): 512 16B-units
        #pragma unroll
        for (int j = 0; j < 2; ++j)
            g2l16(asrc + (j * 256 + t) * 8, ldsa[0] + (j * 256 + w * 64) * 8);
    }
    __syncthreads();                       // drains vmcnt(0): B + A(0) ready

    f32x4 acc[4][4] = {};
    const char* ldsbase = reinterpret_cast<const char*>(ldsx);
    int afoff = (wm << 12) + ((mrow * 4 + kgrp) << 4);   // byte offset of frag 0

    #define LOAD_A_LDS(BUF, AF)                                                  \
        {                                                                        \
            const char* ab_ = reinterpret_cast<const char*>(ldsa[BUF]) + afoff;  \
            _Pragma("unroll")                                                    \
            for (int mi = 0; mi < 4; ++mi)                                       \
                AF[mi] = *reinterpret_cast<const bf16x8*>(ab_ + (mi << 10));     \
        }
    #define LOAD_B(S, BF)                                                        \
        {                                                                        \
            int k_ = (S) >> 2;                                                   \
            int coff_ = ((S) & 3) * 64 + kgrp * 16;                              \
            _Pragma("unroll")                                                    \
            for (int ni = 0; ni < 4; ++ni) {                                     \
                int row_  = wn * 64 + ni * 16 + mrow + k_;                       \
                int addr_ = row_ * 256 + coff_;                                  \
                addr_ ^= (row_ & 7) << 4;                                        \
                BF[ni] = *reinterpret_cast<const bf16x8*>(ldsbase + addr_);      \
            }                                                                    \
        }
    #define STAGE_A(S, BUF)                                                      \
        {                                                                        \
            const u16* as_ = asrc + (size_t)(S) * 8192;                          \
            _Pragma("unroll")                                                    \
            for (int j = 0; j < 2; ++j)                                          \
                g2l16(as_ + (j * 256 + t) * 8, ldsa[BUF] + (j * 256 + w * 64) * 8); \
        }
    #define MFMA16(AF, BF)                                                       \
        {                                                                        \
            _Pragma("unroll")                                                    \
            for (int ni = 0; ni < 4; ++ni)                                       \
                _Pragma("unroll")                                                \
                for (int mi = 0; mi < 4; ++mi)                                   \
                    acc[mi][ni] = __builtin_amdgcn_mfma_f32_16x16x32_bf16(       \
                        AF[mi], BF[ni], acc[mi][ni], 0, 0, 0);                   \
        }

    bf16x8 a0[4], a1[4], b0[4], b1[4];
    LOAD_A_LDS(0, a0);
    LOAD_B(0, b0);

    #pragma unroll 1
    for (int s = 0; s < NSTEP; s += 2) {
        // even step s: A(s) in ldsa[0], regs a0/b0
        if (s + 1 < NSTEP) STAGE_A(s + 1, 1);
        LOAD_B(s + 1, b1);
        MFMA16(a0, b0);
        __syncthreads();                   // A(s+1) staged; ldsa[0] consumers done
        LOAD_A_LDS(1, a1);
        // odd step s+1: A(s+1) in ldsa[1], regs a1/b1
        if (s + 2 < NSTEP) STAGE_A(s + 2, 0);
        LOAD_B(s + 2 < NSTEP ? s + 2 : 0, b0);
        MFMA16(a1, b1);
        __syncthreads();
        LOAD_A_LDS(0, a0);
    }

    // ---- epilogue: D layout col = lane&15 (l), row = (lane>>4)*4 + r (o)
    #pragma unroll
    for (int mi = 0; mi < 4; ++mi) {
        int o0 = obase + wm * 64 + mi * 16 + kgrp * 4;
        f32x4 eb = *reinterpret_cast<const f32x4*>(ebias + o0);
        #pragma unroll
        for (int ni = 0; ni < 4; ++ni) {
            int l = lbase + wn * 64 + ni * 16 + mrow;
            float* op = out + (size_t)(b * C_OUT + o0) * LEN + l;
            #pragma unroll
            for (int r = 0; r < 4; ++r)
                op[(size_t)r * LEN] = acc[mi][ni][r] + eb[r];
        }
    }
    #undef LOAD_A_LDS
    #undef LOAD_B
    #undef STAGE_A
    #undef MFMA16
}

extern "C" void kernel_launch(void* const* d_in, const int* in_sizes, int n_in,
                              void* d_out, int out_size, void* d_ws, size_t ws_size,
                              hipStream_t stream) {
    const float* x      = (const float*)d_in[0];
    const float* weight = (const float*)d_in[1];
    const float* bias   = (const float*)d_in[2];
    const float* vel    = (const float*)d_in[3];
    const float* acc    = (const float*)d_in[4];
    float* out = (float*)d_out;

    char* ws = (char*)d_ws;
    u16*  xt    = (u16*)ws;                                       // 16,797,696 B
    u16*  w3    = (u16*)(ws + (size_t)BATCH * LPAD * C_IN * 2);   // 589,824 B
    float* ebias = (float*)(ws + (size_t)BATCH * LPAD * C_IN * 2 + (size_t)C_OUT * KTOT * 2);

    hipLaunchKernelGGL(prep_xt, dim3((LPAD + 63) / 64, BATCH), dim3(256), 0, stream, x, xt);
    hipLaunchKernelGGL(prep_w3, dim3((C_OUT * KTOT + 255) / 256), dim3(256), 0, stream, weight, w3);
    hipLaunchKernelGGL(prep_ebias, dim3(C_OUT), dim3(256), 0, stream,
                       weight, bias, vel, acc, ebias, out + (size_t)BATCH * C_OUT * LEN);
    hipLaunchKernelGGL(conv_main, dim3(LEN / 128, C_OUT / 128, BATCH), dim3(256), 0, stream,
                       xt, w3, ebias, out);
}

// Round 4
// 61.296 us; speedup vs baseline: 2.3938x; 1.0419x over previous
//
#include <hip/hip_runtime.h>
#include <hip/hip_bf16.h>

typedef unsigned short u16;
typedef __bf16 bf16x8 __attribute__((ext_vector_type(8)));
typedef float f32x4 __attribute__((ext_vector_type(4)));
typedef unsigned short ushort8 __attribute__((ext_vector_type(8)));

#define C_IN   128
#define C_OUT  256
#define BATCH  16
#define LEN    4096
#define KS     9
#define PAD    4
#define LPAD   (LEN + 2*PAD)      // 4104
#define KTOT   (C_IN * KS)        // 1152
#define NSTEP  36                 // K = 1152 / 32

__device__ inline u16 f2bf(float f) {
    __hip_bfloat16 h = __float2bfloat16(f);
    return __builtin_bit_cast(u16, h);
}

// async global->LDS, 16B per lane, wave-uniform LDS base + lane*16
__device__ __forceinline__ void g2l16(const void* g, void* l) {
    __builtin_amdgcn_global_load_lds(
        (const __attribute__((address_space(1))) void*)g,
        (__attribute__((address_space(3))) void*)l, 16, 0, 0);
}

// ---------------------------------------------------------------------------
// Prep 1: x [B][C][L] f32  ->  x_t [B][LPAD][C] bf16, edge-padded, with a
// 4-bit XOR swizzle (16B-block index ^= (l&15)) pre-baked in the global
// layout so the main kernel stages LDS linearly and reads swizzled (rule #21).
// ---------------------------------------------------------------------------
__global__ void prep_xt(const float* __restrict__ x, u16* __restrict__ xt) {
    int b    = blockIdx.y;
    int lane = threadIdx.x & 63;
    int jb   = threadIdx.x >> 6;          // 0..3
    int lp   = blockIdx.x * 64 + lane;    // padded index
    if (lp >= LPAD) return;
    int l = lp - PAD;
    l = l < 0 ? 0 : (l > LEN - 1 ? LEN - 1 : l);   // edge clamp
    const float* xb = x + (size_t)b * C_IN * LEN + l;
    u16* row = xt + ((size_t)b * LPAD + lp) * C_IN;
    int key = lp & 15;
    #pragma unroll
    for (int jj = 0; jj < 4; ++jj) {
        int cblk = jb * 4 + jj;            // channel 16B-block 0..15
        ushort8 v;
        #pragma unroll
        for (int e = 0; e < 8; ++e)
            v[e] = f2bf(xb[(size_t)(cblk * 8 + e) * LEN]);   // coalesced over lanes
        int jstore = cblk ^ key;           // pre-swizzled position (4-bit key)
        *reinterpret_cast<ushort8*>(row + jstore * 8) = v;
    }
}

// ---------------------------------------------------------------------------
// Prep 2 (fused): blocks [0,1152): weight -> w4 in LANE-ORDER fragment layout
//   elem index = ((s*16 + ob16)*64 + kgrp*16 + mrow)*8 + e   (conflict-free
//   ds_read: wave reads lane-contiguous 1KB per frag)
//   where o = ob16*16+mrow, k = s>>2, c = (s&3)*32 + kgrp*8 + e.
// blocks [1152, 1408): ebias[o] = bias[o] + sum offset*W; block 1152: phys.
// ---------------------------------------------------------------------------
__global__ void prep_wb(const float* __restrict__ w, const float* __restrict__ bias,
                        const float* __restrict__ vel, const float* __restrict__ acc,
                        u16* __restrict__ w4, float* __restrict__ ebias,
                        float* __restrict__ phys_out) {
    int t = threadIdx.x;
    if (blockIdx.x < 1152) {
        int i = blockIdx.x * 256 + t;      // exact: 1152*256 == C_OUT*KTOT
        int e  = i & 7;
        int r  = i >> 3;
        int mr = r & 15;
        int kg = (r >> 4) & 3;
        int ob = (r >> 6) & 15;
        int s  = r >> 10;
        int o  = ob * 16 + mr;
        int k  = s >> 2;
        int c  = (s & 3) * 32 + kg * 8 + e;
        w4[i] = f2bf(w[((size_t)o * C_IN + c) * KS + k]);
        return;
    }
    __shared__ float red[256];
    int o = blockIdx.x - 1152;
    float sum = 0.f;
    for (int i = t; i < KTOT; i += 256) {
        int k = i % KS;                    // offset layout [c][k]
        float tk = k * 0.01f;              // DT
        float off = vel[i] * tk + 0.5f * acc[i] * tk * tk;
        sum += off * w[(size_t)o * KTOT + i];
    }
    red[t] = sum;
    __syncthreads();
    for (int h = 128; h > 0; h >>= 1) {
        if (t < h) red[t] += red[t + h];
        __syncthreads();
    }
    if (t == 0) ebias[o] = bias[o] + red[0];

    if (o == 0) {                          // phys
        __syncthreads();
        float pv = 0.f;
        for (int i = t; i < KTOT; i += 256) {
            float v = vel[i], a = acc[i];
            pv += v * v + a * a;
        }
        red[t] = pv;
        __syncthreads();
        for (int h = 128; h > 0; h >>= 1) {
            if (t < h) red[t] += red[t + h];
            __syncthreads();
        }
        if (t == 0) *phys_out = 0.01f * (red[0] / (float)KTOT);
    }
}

// ---------------------------------------------------------------------------
// Main: implicit-GEMM conv. Block = 128 o x 128 l, 4 waves (2x2), each wave
// 4x4 frags of mfma_f32_16x16x32_bf16.
//  - B (x-tile) staged ONCE via global_load_lds (4-bit swizzle baked in data)
//  - A ring of 4 LDS buffers, stage distance 3, counted vmcnt(2) (never 0
//    mid-loop) + lgkmcnt(0) read-protect + raw s_barrier (T3/T4)
//  - fully unrolled 36-step loop: all buffer indices & waits compile-time
// ---------------------------------------------------------------------------
__global__ __launch_bounds__(256, 2) void conv_main(const u16* __restrict__ xt,
                                                    const u16* __restrict__ w4,
                                                    const float* __restrict__ ebias,
                                                    float* __restrict__ out) {
    __shared__ u16 ldsx[17408];            // B tile, 34816 B
    __shared__ u16 ldsa[4][4096];          // A ring, 4 x 8192 B

    int b     = blockIdx.z;
    int obase = blockIdx.y * 128;
    int lbase = blockIdx.x * 128;
    int t     = threadIdx.x;
    int lane  = t & 63;
    int w     = t >> 6;
    int wm    = w >> 1;                    // wave row (o)
    int wn    = w & 1;                     // wave col (l)
    int mrow  = lane & 15;
    int kgrp  = lane >> 4;

    // A-panel source: 8 ob16 groups starting at obase/16; stride/step = 8192 u16
    const u16* asrc = w4 + (size_t)(obase >> 4) * 512;

    // ---- prologue: stage B (34816B) + A(0..2) via global_load_lds
    {
        const u16* bsrc = xt + ((size_t)b * LPAD + lbase) * C_IN;
        #pragma unroll
        for (int j = 0; j < 8; ++j)
            g2l16(bsrc + (j * 256 + t) * 8, ldsx + (j * 256 + w * 64) * 8);
        if (t < 128)
            g2l16(bsrc + (2048 + t) * 8, ldsx + (2048 + w * 64) * 8);
        #pragma unroll
        for (int p = 0; p < 3; ++p)
            #pragma unroll
            for (int j = 0; j < 2; ++j)
                g2l16(asrc + (size_t)p * 8192 + (j * 256 + t) * 8,
                      ldsa[p] + (j * 256 + w * 64) * 8);
    }
    __syncthreads();                       // drains everything: B + A(0..2) ready

    f32x4 acc[4][4] = {};
    const char* ldsbase = reinterpret_cast<const char*>(ldsx);
    int afoff = (wm << 12) + lane * 16;    // lane-contiguous A frag base

    #define LOAD_A_BUF(BUF, AF)                                                  \
        {                                                                        \
            const char* ab_ = reinterpret_cast<const char*>(ldsa[BUF]) + afoff;  \
            _Pragma("unroll")                                                    \
            for (int mi = 0; mi < 4; ++mi)                                       \
                AF[mi] = *reinterpret_cast<const bf16x8*>(ab_ + (mi << 10));     \
        }
    #define LOAD_B(S, BF)                                                        \
        {                                                                        \
            int k_ = (S) >> 2;                                                   \
            int coff_ = ((S) & 3) * 64 + kgrp * 16;                              \
            _Pragma("unroll")                                                    \
            for (int ni = 0; ni < 4; ++ni) {                                     \
                int row_  = wn * 64 + ni * 16 + mrow + k_;                       \
                int addr_ = row_ * 256 + coff_;                                  \
                addr_ ^= (row_ & 15) << 4;                                       \
                BF[ni] = *reinterpret_cast<const bf16x8*>(ldsbase + addr_);      \
            }                                                                    \
        }
    #define STAGE_A(S, BUF)                                                      \
        {                                                                        \
            const u16* as_ = asrc + (size_t)(S) * 8192;                          \
            _Pragma("unroll")                                                    \
            for (int j = 0; j < 2; ++j)                                          \
                g2l16(as_ + (j * 256 + t) * 8, ldsa[BUF] + (j * 256 + w * 64) * 8); \
        }
    #define MFMA16(AF, BF)                                                       \
        {                                                                        \
            _Pragma("unroll")                                                    \
            for (int ni = 0; ni < 4; ++ni)                                       \
                _Pragma("unroll")                                                \
                for (int mi = 0; mi < 4; ++mi)                                   \
                    acc[mi][ni] = __builtin_amdgcn_mfma_f32_16x16x32_bf16(       \
                        AF[mi], BF[ni], acc[mi][ni], 0, 0, 0);                   \
        }

    bf16x8 ar[2][4], br[2][4];
    LOAD_A_BUF(0, ar[0]);
    LOAD_B(0, br[0]);

    // Pipeline invariants (ring=4, distance=3):
    //  - end-of-step-s wait vmcnt(2) leaves only stage(s+3) outstanding
    //    => stage(s+2) landed => step s+1's LOAD_A(s+2) is safe
    //  - lgkmcnt(0) before each barrier => this step's ds_reads complete
    //    => buffer overwritten 2+ barriers later is race-free
    #pragma unroll
    for (int s = 0; s < NSTEP; ++s) {
        const int cur = s & 1, nx = cur ^ 1;
        if (s + 3 < NSTEP) STAGE_A(s + 3, (s + 3) & 3);
        if (s + 1 < NSTEP) { LOAD_A_BUF((s + 1) & 3, ar[nx]); LOAD_B(s + 1, br[nx]); }
        MFMA16(ar[cur], br[cur]);
        if (s + 1 < NSTEP) {
            if (s + 3 < NSTEP) asm volatile("s_waitcnt vmcnt(2)" ::: "memory");
            else               asm volatile("s_waitcnt vmcnt(0)" ::: "memory");
            asm volatile("s_waitcnt lgkmcnt(0)" ::: "memory");
            __builtin_amdgcn_s_barrier();
        }
    }

    // ---- epilogue: D layout col = lane&15 (l), row = (lane>>4)*4 + r (o)
    #pragma unroll
    for (int mi = 0; mi < 4; ++mi) {
        int o0 = obase + wm * 64 + mi * 16 + kgrp * 4;
        f32x4 eb = *reinterpret_cast<const f32x4*>(ebias + o0);
        #pragma unroll
        for (int ni = 0; ni < 4; ++ni) {
            int l = lbase + wn * 64 + ni * 16 + mrow;
            float* op = out + (size_t)(b * C_OUT + o0) * LEN + l;
            #pragma unroll
            for (int r = 0; r < 4; ++r)
                op[(size_t)r * LEN] = acc[mi][ni][r] + eb[r];
        }
    }
    #undef LOAD_A_BUF
    #undef LOAD_B
    #undef STAGE_A
    #undef MFMA16
}

extern "C" void kernel_launch(void* const* d_in, const int* in_sizes, int n_in,
                              void* d_out, int out_size, void* d_ws, size_t ws_size,
                              hipStream_t stream) {
    const float* x      = (const float*)d_in[0];
    const float* weight = (const float*)d_in[1];
    const float* bias   = (const float*)d_in[2];
    const float* vel    = (const float*)d_in[3];
    const float* acc    = (const float*)d_in[4];
    float* out = (float*)d_out;

    char* ws = (char*)d_ws;
    u16*  xt    = (u16*)ws;                                       // 16,797,696 B
    u16*  w4    = (u16*)(ws + (size_t)BATCH * LPAD * C_IN * 2);   // 589,824 B
    float* ebias = (float*)(ws + (size_t)BATCH * LPAD * C_IN * 2 + (size_t)C_OUT * KTOT * 2);

    hipLaunchKernelGGL(prep_xt, dim3((LPAD + 63) / 64, BATCH), dim3(256), 0, stream, x, xt);
    hipLaunchKernelGGL(prep_wb, dim3(1152 + 256), dim3(256), 0, stream,
                       weight, bias, vel, acc, w4, ebias, out + (size_t)BATCH * C_OUT * LEN);
    hipLaunchKernelGGL(conv_main, dim3(LEN / 128, C_OUT / 128, BATCH), dim3(256), 0, stream,
                       xt, w4, ebias, out);
}

// Round 5
// 58.572 us; speedup vs baseline: 2.5051x; 1.0465x over previous
//
#include <hip/hip_runtime.h>
#include <hip/hip_bf16.h>

typedef unsigned short u16;
typedef __bf16 bf16x8 __attribute__((ext_vector_type(8)));
typedef float f32x4 __attribute__((ext_vector_type(4)));
typedef unsigned short ushort8 __attribute__((ext_vector_type(8)));

#define C_IN   128
#define C_OUT  256
#define BATCH  16
#define LEN    4096
#define KS     9
#define PAD    4
#define LPAD   (LEN + 2*PAD)      // 4104
#define KTOT   (C_IN * KS)        // 1152
#define NSTEP  36                 // K = 1152 / 32

#define XT_BLKS    1040           // 65 * 16
#define W4_BLKS    1152
#define EB_BLKS    256

__device__ inline u16 f2bf(float f) {
    __hip_bfloat16 h = __float2bfloat16(f);
    return __builtin_bit_cast(u16, h);
}

// async global->LDS, 16B per lane, wave-uniform LDS base + lane*16
__device__ __forceinline__ void g2l16(const void* g, void* l) {
    __builtin_amdgcn_global_load_lds(
        (const __attribute__((address_space(1))) void*)g,
        (__attribute__((address_space(3))) void*)l, 16, 0, 0);
}

// ---------------------------------------------------------------------------
// Fused prep (one launch):
//  blocks [0,1040): x [B][C][L] f32 -> xt [B][LPAD][C] bf16, edge-padded,
//    4-bit XOR swizzle (16B-block idx ^= l&15) baked into global layout.
//  blocks [1040,2192): weight -> w4 lane-order fragment layout
//    elem = ((s*16 + ob16)*64 + kgrp*16 + mrow)*8 + e,
//    o = ob16*16+mrow, k = s>>2, c = (s&3)*32+kgrp*8+e.
//  blocks [2192,2448): ebias[o] = bias[o] + sum offset*W; block 2192: phys.
// ---------------------------------------------------------------------------
__global__ void prep_all(const float* __restrict__ x, const float* __restrict__ w,
                         const float* __restrict__ bias, const float* __restrict__ vel,
                         const float* __restrict__ acc_in,
                         u16* __restrict__ xt, u16* __restrict__ w4,
                         float* __restrict__ ebias, float* __restrict__ phys_out) {
    int bid = blockIdx.x;
    int t = threadIdx.x;
    if (bid < XT_BLKS) {
        int b    = bid / 65;
        int lblk = bid % 65;
        int lane = t & 63;
        int jb   = t >> 6;
        int lp   = lblk * 64 + lane;
        if (lp >= LPAD) return;
        int l = lp - PAD;
        l = l < 0 ? 0 : (l > LEN - 1 ? LEN - 1 : l);
        const float* xb = x + (size_t)b * C_IN * LEN + l;
        u16* row = xt + ((size_t)b * LPAD + lp) * C_IN;
        int key = lp & 15;
        #pragma unroll
        for (int jj = 0; jj < 4; ++jj) {
            int cblk = jb * 4 + jj;
            ushort8 v;
            #pragma unroll
            for (int e = 0; e < 8; ++e)
                v[e] = f2bf(xb[(size_t)(cblk * 8 + e) * LEN]);
            int jstore = cblk ^ key;
            *reinterpret_cast<ushort8*>(row + jstore * 8) = v;
        }
        return;
    }
    if (bid < XT_BLKS + W4_BLKS) {
        int i = (bid - XT_BLKS) * 256 + t;   // exact: 1152*256 == C_OUT*KTOT
        int e  = i & 7;
        int r  = i >> 3;
        int mr = r & 15;
        int kg = (r >> 4) & 3;
        int ob = (r >> 6) & 15;
        int s  = r >> 10;
        int o  = ob * 16 + mr;
        int k  = s >> 2;
        int c  = (s & 3) * 32 + kg * 8 + e;
        w4[i] = f2bf(w[((size_t)o * C_IN + c) * KS + k]);
        return;
    }
    __shared__ float red[256];
    int o = bid - (XT_BLKS + W4_BLKS);
    float sum = 0.f;
    for (int i = t; i < KTOT; i += 256) {
        int k = i % KS;                    // offset layout [c][k]
        float tk = k * 0.01f;              // DT
        float off = vel[i] * tk + 0.5f * acc_in[i] * tk * tk;
        sum += off * w[(size_t)o * KTOT + i];
    }
    red[t] = sum;
    __syncthreads();
    for (int h = 128; h > 0; h >>= 1) {
        if (t < h) red[t] += red[t + h];
        __syncthreads();
    }
    if (t == 0) ebias[o] = bias[o] + red[0];

    if (o == 0) {                          // phys
        __syncthreads();
        float pv = 0.f;
        for (int i = t; i < KTOT; i += 256) {
            float v = vel[i], a = acc_in[i];
            pv += v * v + a * a;
        }
        red[t] = pv;
        __syncthreads();
        for (int h = 128; h > 0; h >>= 1) {
            if (t < h) red[t] += red[t + h];
            __syncthreads();
        }
        if (t == 0) *phys_out = 0.01f * (red[0] / (float)KTOT);
    }
}

// ---------------------------------------------------------------------------
// Main: implicit-GEMM conv. Block = 256 o x 128 l (all of C_out), 4 waves
// (2 wm x 2 wn), wave tile 128 o x 64 l = 8x4 frags of mfma_f32_16x16x32_bf16
// (43.7 MFMA-FLOP per LDS byte, vs 32 for 4x4 — LDS pipe was the binding
// constraint at R4).
//  - B (x-tile, 34816B) staged ONCE via global_load_lds (swizzle in data)
//  - A double-buffered 2 x 16KB/step, shared by all 4 waves
//  - per-step vmcnt(0)+lgkmcnt(0)+s_barrier: drain is covered by the
//    ~1240-cyc/SIMD MFMA phase; 2 blocks/CU stagger the barriers
// ---------------------------------------------------------------------------
__global__ __launch_bounds__(256, 2) void conv_main(const u16* __restrict__ xt,
                                                    const u16* __restrict__ w4,
                                                    const float* __restrict__ ebias,
                                                    float* __restrict__ out) {
    __shared__ u16 ldsx[17408];            // B tile, 34816 B
    __shared__ u16 ldsa[2][8192];          // A dbuf, 2 x 16384 B

    int b     = blockIdx.y;
    int lbase = blockIdx.x * 128;
    int t     = threadIdx.x;
    int lane  = t & 63;
    int w     = t >> 6;
    int wm    = w >> 1;                    // wave o-half (0/1 -> o 0..127 / 128..255)
    int wn    = w & 1;                     // wave l-half
    int mrow  = lane & 15;
    int kgrp  = lane >> 4;

    // ---- prologue: stage B (34816B) + A(0) via global_load_lds
    {
        const u16* bsrc = xt + ((size_t)b * LPAD + lbase) * C_IN;
        #pragma unroll
        for (int j = 0; j < 8; ++j)
            g2l16(bsrc + (j * 256 + t) * 8, ldsx + (j * 256 + w * 64) * 8);
        if (t < 128)
            g2l16(bsrc + (2048 + t) * 8, ldsx + (2048 + w * 64) * 8);
        #pragma unroll
        for (int j = 0; j < 4; ++j)
            g2l16(w4 + (j * 256 + t) * 8, ldsa[0] + (j * 256 + w * 64) * 8);
    }
    __syncthreads();                       // drains vmcnt(0): B + A(0) ready

    f32x4 acc[8][4] = {};
    const char* ldsbase = reinterpret_cast<const char*>(ldsx);
    int afoff = (wm << 13) + lane * 16;    // + mi*1024 per frag

    #define LOAD_A_BUF(BUF, AF)                                                  \
        {                                                                        \
            const char* ab_ = reinterpret_cast<const char*>(ldsa[BUF]) + afoff;  \
            _Pragma("unroll")                                                    \
            for (int mi = 0; mi < 8; ++mi)                                       \
                AF[mi] = *reinterpret_cast<const bf16x8*>(ab_ + (mi << 10));     \
        }
    #define LOAD_B(S, BF)                                                        \
        {                                                                        \
            int k_ = (S) >> 2;                                                   \
            int coff_ = ((S) & 3) * 64 + kgrp * 16;                              \
            _Pragma("unroll")                                                    \
            for (int ni = 0; ni < 4; ++ni) {                                     \
                int row_  = wn * 64 + ni * 16 + mrow + k_;                       \
                int addr_ = row_ * 256 + coff_;                                  \
                addr_ ^= (row_ & 15) << 4;                                       \
                BF[ni] = *reinterpret_cast<const bf16x8*>(ldsbase + addr_);      \
            }                                                                    \
        }
    #define STAGE_A(S, BUF)                                                      \
        {                                                                        \
            const u16* as_ = w4 + (size_t)(S) * 8192;                            \
            _Pragma("unroll")                                                    \
            for (int j = 0; j < 4; ++j)                                          \
                g2l16(as_ + (j * 256 + t) * 8, ldsa[BUF] + (j * 256 + w * 64) * 8); \
        }

    #pragma unroll
    for (int s = 0; s < NSTEP; ++s) {
        if (s + 1 < NSTEP) STAGE_A(s + 1, (s + 1) & 1);
        bf16x8 af[8], bf[4];
        LOAD_A_BUF(s & 1, af);
        LOAD_B(s, bf);
        #pragma unroll
        for (int mi = 0; mi < 8; ++mi)
            #pragma unroll
            for (int ni = 0; ni < 4; ++ni)
                acc[mi][ni] = __builtin_amdgcn_mfma_f32_16x16x32_bf16(
                    af[mi], bf[ni], acc[mi][ni], 0, 0, 0);
        if (s + 1 < NSTEP) {
            // A(s+1) staged (vmcnt) + my reads of ldsa[s&1] done (lgkm),
            // then barrier => safe to overwrite ldsa[s&1] at step s+1
            asm volatile("s_waitcnt vmcnt(0) lgkmcnt(0)" ::: "memory");
            __builtin_amdgcn_s_barrier();
        }
    }

    // ---- epilogue: D layout col = lane&15 (l), row = (lane>>4)*4 + r (o)
    #pragma unroll
    for (int mi = 0; mi < 8; ++mi) {
        int o0 = wm * 128 + mi * 16 + kgrp * 4;
        f32x4 eb = *reinterpret_cast<const f32x4*>(ebias + o0);
        #pragma unroll
        for (int ni = 0; ni < 4; ++ni) {
            int l = lbase + wn * 64 + ni * 16 + mrow;
            float* op = out + (size_t)(b * C_OUT + o0) * LEN + l;
            #pragma unroll
            for (int r = 0; r < 4; ++r)
                op[(size_t)r * LEN] = acc[mi][ni][r] + eb[r];
        }
    }
    #undef LOAD_A_BUF
    #undef LOAD_B
    #undef STAGE_A
}

extern "C" void kernel_launch(void* const* d_in, const int* in_sizes, int n_in,
                              void* d_out, int out_size, void* d_ws, size_t ws_size,
                              hipStream_t stream) {
    const float* x      = (const float*)d_in[0];
    const float* weight = (const float*)d_in[1];
    const float* bias   = (const float*)d_in[2];
    const float* vel    = (const float*)d_in[3];
    const float* acc    = (const float*)d_in[4];
    float* out = (float*)d_out;

    char* ws = (char*)d_ws;
    u16*  xt    = (u16*)ws;                                       // 16,797,696 B
    u16*  w4    = (u16*)(ws + (size_t)BATCH * LPAD * C_IN * 2);   // 589,824 B
    float* ebias = (float*)(ws + (size_t)BATCH * LPAD * C_IN * 2 + (size_t)C_OUT * KTOT * 2);

    hipLaunchKernelGGL(prep_all, dim3(XT_BLKS + W4_BLKS + EB_BLKS), dim3(256), 0, stream,
                       x, weight, bias, vel, acc, xt, w4, ebias,
                       out + (size_t)BATCH * C_OUT * LEN);
    hipLaunchKernelGGL(conv_main, dim3(LEN / 128, BATCH), dim3(256), 0, stream,
                       xt, w4, ebias, out);
}